// Round 10
// baseline (314.094 us; speedup 1.0000x reference)
//
#include <hip/hip_runtime.h>

// B=8, N=32, T=64, D=128, E=4, H=32, BT=512
// R10: grid 1024 (bt, half) x 512 threads. Q/K stored as bf16 A-frags (content
// in fp32 VALU from bf16 pairs). LDS ~35 KB -> 4 blocks/CU = 32 waves/CU (max).

typedef __bf16 bf16x8 __attribute__((ext_vector_type(8)));
typedef float  f32x4  __attribute__((ext_vector_type(4)));

static __device__ __forceinline__ unsigned short f2bf(float f) {
    unsigned u = __float_as_uint(f);
    u += 0x7fffu + ((u >> 16) & 1u);        // RNE
    return (unsigned short)(u >> 16);
}
static __device__ __forceinline__ float bf2f(unsigned short u) {
    return __uint_as_float(((unsigned)u) << 16);
}
static __device__ __forceinline__ unsigned pack2(float a, float b) {
    return (unsigned)f2bf(a) | ((unsigned)f2bf(b) << 16);
}
static __device__ __forceinline__ float blo(unsigned u) { return __uint_as_float(u << 16); }
static __device__ __forceinline__ float bhi(unsigned u) { return __uint_as_float(u & 0xffff0000u); }

// Wfrag (16B chunks): [0,2048) Wq | [2048,4096) Wk | [4096,6144) Wv |
// [6144,8192) Theta | chunk 8192+: Cq=W1q@Wq (512), chunk 8704+: Ck=W1k@Wk (512).
__global__ __launch_bounds__(256) void k0a_pack_w(
    const float* __restrict__ Wq, const float* __restrict__ Wk,
    const float* __restrict__ Wv, const float* __restrict__ Theta,
    unsigned short* __restrict__ Wfrag)
{
    int gid = blockIdx.x * 256 + threadIdx.x;      // 0..8191
    int g = gid >> 11, c = gid & 2047;
    int ntk = c >> 6, lane = c & 63;
    int i = (ntk >> 2) * 16 + (lane & 15);
    int j = (ntk & 3) * 32 + (lane >> 4) * 8;
    const float* src = (g == 0 ? Wq : g == 1 ? Wk : g == 2 ? Wv : Theta) + (size_t)i * 128 + j;
    float4 a = *(const float4*)(src);
    float4 b = *(const float4*)(src + 4);
    uint4 pk;
    pk.x = pack2(a.x, a.y); pk.y = pack2(a.z, a.w);
    pk.z = pack2(b.x, b.y); pk.w = pack2(b.z, b.w);
    *(uint4*)(Wfrag + (size_t)gid * 8) = pk;
}

__global__ __launch_bounds__(256, 1) void k0b_compose(
    const float* __restrict__ Wq, const float* __restrict__ Wk,
    const float* __restrict__ W1, unsigned short* __restrict__ Wfrag)
{
    __shared__ __align__(16) float Ws[128 * 132];
    __shared__ __align__(16) float W1s[8 * 128];
    const int tid = threadIdx.x;
    const int mat   = blockIdx.x & 1;
    const int hbase = (blockIdx.x >> 1) * 8;
    const float* Wsel = mat ? Wk : Wq;
#pragma unroll
    for (int q = 0; q < 16; ++q) {
        int f = tid + 256 * q;
        int i = f >> 5, c4 = (f & 31) * 4;
        *(float4*)(Ws + i * 132 + c4) = *(const float4*)(Wsel + (size_t)i * 128 + c4);
    }
#pragma unroll
    for (int q = 0; q < 4; ++q) {
        int f = tid + 256 * q;
        int hl = f >> 7, i = f & 127;
        W1s[hl * 128 + i] = W1[(size_t)(hbase + hl) * 260 + mat * 128 + i];
    }
    __syncthreads();
    const int hl = tid >> 5;
    const int h  = hbase + hl;
    const int j0 = (tid & 31) * 4;
    float4 acc = {0.f, 0.f, 0.f, 0.f};
    for (int i = 0; i < 128; ++i) {
        float c = W1s[hl * 128 + i];
        float4 w = *(const float4*)(Ws + i * 132 + j0);
        acc.x = fmaf(c, w.x, acc.x); acc.y = fmaf(c, w.y, acc.y);
        acc.z = fmaf(c, w.z, acc.z); acc.w = fmaf(c, w.w, acc.w);
    }
    const int nt = h >> 4;
    const unsigned base = 65536u + (unsigned)mat * 4096u;   // shorts
    float av[4] = {acc.x, acc.y, acc.z, acc.w};
#pragma unroll
    for (int jj = 0; jj < 4; ++jj) {
        int j = j0 + jj;
        int lane = (h & 15) | (((j >> 3) & 3) << 4);
        int ks = j >> 5, vj = j & 7;
        Wfrag[base + (unsigned)((nt * 4 + ks) * 64 + lane) * 8 + vj] = f2bf(av[jj]);
    }
}

__global__ __launch_bounds__(512, 8)
void gnn_fused(const float* __restrict__ x,
               const float* __restrict__ edge,
               const float* __restrict__ A_prior,
               const unsigned char* __restrict__ pad_mask,
               const unsigned short* __restrict__ Wfrag,
               const float* __restrict__ Wfuse,
               const float* __restrict__ W1,
               const float* __restrict__ b1,
               const float* __restrict__ W2,
               const float* __restrict__ b2,
               const float* __restrict__ gma,
               const float* __restrict__ bta,
               const float* __restrict__ physw,
               const float* __restrict__ priorw,
               float* __restrict__ out)
{
    __shared__ __align__(16) unsigned char arena[35040];
    // [0,8192):      Zfrag bf16 A-frags (32 tok) -> Sfrag (16 rows, first 4KB)
    // [8192,16384):  Kfrag bf16 A-frags (32 tok) -> ThOut fp32 16x128
    // [16384,24576): Vfrag bf16 A-frags (32 tok)
    // [24576,28672): Qfrag bf16 A-frags (16 rows)
    // [28672,30784): Lg fp32 16x33
    // [30784,31936): hqT bf16 [h][nl] stride 18 (b1 folded)
    // [31936,34112): hks bf16 [m][h] stride 34
    unsigned short* Zfrag = (unsigned short*)(arena);
    unsigned short* Sfrag = (unsigned short*)(arena);
    unsigned short* Kfrag = (unsigned short*)(arena + 8192);
    float*          ThOut = (float*)(arena + 8192);
    unsigned short* Vfrag = (unsigned short*)(arena + 16384);
    unsigned short* Qfrag = (unsigned short*)(arena + 24576);
    float*          Lg    = (float*)(arena + 28672);
    unsigned short* hqT   = (unsigned short*)(arena + 30784);
    unsigned short* hks   = (unsigned short*)(arena + 31936);
    float4* W1e_s  = (float4*)(arena + 34112);
    float*  W2_s   = (float*)(arena + 34624);
    float*  b1s    = (float*)(arena + 34752);
    float*  maskrow= (float*)(arena + 34880);
    float*  Wf_s   = (float*)(arena + 35008);

    const int tid  = threadIdx.x;            // 0..511
    const int bt   = blockIdx.x >> 1;
    const int half = blockIdx.x & 1;
    const int b_ = bt >> 6, t_ = bt & 63;
    const float pw  = physw[0];
    const float rw_ = priorw[0];
    const float b2v = b2[0];

    // ---- P0: prefetch edge/prior/x-row into regs; stage Z A-frags; small weights ----
    const int m3 = tid & 31;                 // key token (P3/P6/P8 col group)
    const int nl = tid >> 5;                 // local q row 0..15
    const int ng = half * 16 + nl;           // global q row
    float4 e4;
    float pr5[5];
    float4 xreg;
    {
        e4 = *(const float4*)(edge + (((size_t)bt * 32 + ng) * 32 + m3) * 4);
        size_t pb = (((size_t)bt * 32 + ng) * 32 + m3) * 5;
#pragma unroll
        for (int j5 = 0; j5 < 5; ++j5) pr5[j5] = A_prior[pb + j5];
        xreg = *(const float4*)(x + ((size_t)((b_ * 32 + ng) * 64 + t_)) * 128 + m3 * 4);
    }
    {
        int f = tid;                          // one chunk per thread
        int lane9 = f & 63, ntk = f >> 6;
        int mm = lane9 & 15, qq = lane9 >> 4;
        int n = (ntk >> 2) * 16 + mm;
        int d = (ntk & 3) * 32 + qq * 8;
        const float* xr = x + ((size_t)((b_ * 32 + n) * 64 + t_)) * 128 + d;
        float4 a = *(const float4*)(xr);
        float4 b = *(const float4*)(xr + 4);
        uint4 pk;
        pk.x = pack2(a.x, a.y); pk.y = pack2(a.z, a.w);
        pk.z = pack2(b.x, b.y); pk.w = pack2(b.z, b.w);
        *(uint4*)(Zfrag + f * 8) = pk;
    }
    if (tid < 32) {
        int h = tid;
        W1e_s[h] = *(const float4*)(W1 + (size_t)h * 260 + 256);
        W2_s[h]  = W2[h];
        b1s[h]   = b1[h];
        maskrow[h] = pad_mask[b_ * 32 + h] ? 1.f : 0.f;
        if (h < 5) Wf_s[h] = Wfuse[h];
    }
    __syncthreads();

    const int w    = tid >> 6;        // wave 0..7
    const int lane = tid & 63;
    const int quad = lane >> 4;
    const int col0 = lane & 15;
    const bf16x8* Wf = (const bf16x8*)Wfrag;

    // ---- P1: K,V (32 tok, 2 col-tiles/wave), Q (16 rows, 1 tile/wave), hq, hk ----
    {
        const int Mt = w & 1;          // K/V token half (also hk token half for w>=4)
        const int cg = w >> 1;         // K/V col group
        f32x4 zero = {0.f, 0.f, 0.f, 0.f};
        f32x4 aK[2] = {zero, zero};
        f32x4 aV[2] = {zero, zero};
        f32x4 aQ = zero, aH = zero;
#pragma unroll
        for (int ks = 0; ks < 4; ++ks) {
            bf16x8 avK = *(const bf16x8*)(Zfrag + ((Mt * 4 + ks) * 64 + lane) * 8);
            bf16x8 avQ = *(const bf16x8*)(Zfrag + ((half * 4 + ks) * 64 + lane) * 8);
#pragma unroll
            for (int j = 0; j < 2; ++j) {
                int nt = cg * 2 + j;
                int bi = (nt * 4 + ks) * 64 + lane;
                aK[j] = __builtin_amdgcn_mfma_f32_16x16x32_bf16(avK, Wf[bi + 2048], aK[j], 0, 0, 0);
                aV[j] = __builtin_amdgcn_mfma_f32_16x16x32_bf16(avK, Wf[bi + 4096], aV[j], 0, 0, 0);
            }
            aQ = __builtin_amdgcn_mfma_f32_16x16x32_bf16(avQ, Wf[(w * 4 + ks) * 64 + lane], aQ, 0, 0, 0);
            if (w < 2)
                aH = __builtin_amdgcn_mfma_f32_16x16x32_bf16(avQ, Wf[8192 + (w * 4 + ks) * 64 + lane], aH, 0, 0, 0);
            else if (w >= 4)
                aH = __builtin_amdgcn_mfma_f32_16x16x32_bf16(avK, Wf[8704 + (((w - 4) >> 1) * 4 + ks) * 64 + lane], aH, 0, 0, 0);
        }
        // K,V writes (fresh regions; no alias with Zfrag)
#pragma unroll
        for (int j = 0; j < 2; ++j) {
            int colc = (cg * 2 + j) * 16 + col0;
            int vks = colc >> 5, vq = (colc >> 3) & 3, vj = colc & 7;
#pragma unroll
            for (int reg = 0; reg < 4; ++reg) {
                int tok = Mt * 16 + quad * 4 + reg;
                int idx = (Mt * 4 + vks) * 64 + vq * 16 + (tok & 15);
                Kfrag[idx * 8 + vj] = f2bf(aK[j][reg]);
                Vfrag[idx * 8 + vj] = f2bf(aV[j][reg]);
            }
        }
        {
            int colc = w * 16 + col0;
            int vks = colc >> 5, vq = (colc >> 3) & 3, vj = colc & 7;
#pragma unroll
            for (int reg = 0; reg < 4; ++reg)
                Qfrag[(vks * 64 + vq * 16 + (quad * 4 + reg)) * 8 + vj] = f2bf(aQ[reg]);
        }
        if (w < 2) {
            int h = w * 16 + col0;
#pragma unroll
            for (int reg = 0; reg < 4; ++reg)
                hqT[h * 18 + (quad * 4 + reg)] = f2bf(aH[reg] + b1s[h]);
        } else if (w >= 4) {
            int h = ((w - 4) >> 1) * 16 + col0;
#pragma unroll
            for (int reg = 0; reg < 4; ++reg)
                hks[(Mt * 16 + quad * 4 + reg) * 34 + h] = f2bf(aH[reg]);
        }
    }
    __syncthreads();

    // ---- P3: one (q=nl, key=m3) pair per thread: content fp32 from bf16 frags + MLP + prior ----
    {
        const int m = m3;
        float acc = 0.f;
#pragma unroll
        for (int ks = 0; ks < 4; ++ks) {
#pragma unroll
            for (int vq = 0; vq < 4; ++vq) {
                uint4 qu = *(const uint4*)(Qfrag + (ks * 64 + vq * 16 + nl) * 8);
                uint4 ku = *(const uint4*)(Kfrag + (((m >> 4) * 4 + ks) * 64 + vq * 16 + (m & 15)) * 8);
                acc = fmaf(blo(qu.x), blo(ku.x), fmaf(bhi(qu.x), bhi(ku.x), acc));
                acc = fmaf(blo(qu.y), blo(ku.y), fmaf(bhi(qu.y), bhi(ku.y), acc));
                acc = fmaf(blo(qu.z), blo(ku.z), fmaf(bhi(qu.z), bhi(ku.z), acc));
                acc = fmaf(blo(qu.w), blo(ku.w), fmaf(bhi(qu.w), bhi(ku.w), acc));
            }
        }
        float pacc = 0.f;
        for (int h = 0; h < 32; ++h) {
            float4 we = W1e_s[h];
            float hkv = bf2f(hks[m * 34 + h]);
            float hqv = bf2f(hqT[h * 18 + nl]);
            float he  = fmaf(e4.x, we.x, fmaf(e4.y, we.y, fmaf(e4.z, we.z, e4.w * we.w)));
            pacc = fmaf(fmaxf(hqv + hkv + he, 0.f), W2_s[h], pacc);
        }
        float pr = pr5[0]*Wf_s[0] + pr5[1]*Wf_s[1] + pr5[2]*Wf_s[2]
                 + pr5[3]*Wf_s[3] + pr5[4]*Wf_s[4];
        if (!(fabsf(pr) < 1e30f)) pr = 0.f;
        pr = fmaxf(pr, 0.f);
        float lg = acc * 0.08838834764831845f
                 + pw * (pacc + b2v) + rw_ * __logf(pr + 1e-6f);
        if (maskrow[ng] != 0.f || maskrow[m] != 0.f) lg = -1e9f;
        Lg[nl * 33 + m] = lg;
    }
    __syncthreads();

    // ---- P4: softmax (16 rows) ----
    if (tid < 16) {
        const int n = tid;
        float mx = -3.4e38f;
        for (int m2 = 0; m2 < 32; ++m2) mx = fmaxf(mx, Lg[n * 33 + m2]);
        float s = 0.f;
        for (int m2 = 0; m2 < 32; ++m2) {
            float e = __expf(Lg[n * 33 + m2] - mx);
            Lg[n * 33 + m2] = e; s += e;
        }
        float inv = 1.f / s;
        for (int m2 = 0; m2 < 32; ++m2) Lg[n * 33 + m2] *= inv;
    }
    __syncthreads();

    // ---- P6: spatial = alpha @ V (1 row x 4 cols per thread) -> Sfrag (Zfrag region) ----
    {
        const int d0 = m3 * 4;
        const int vks = d0 >> 5, vq = (d0 >> 3) & 3, vj = d0 & 7;
        float sa0 = 0.f, sa1 = 0.f, sa2 = 0.f, sa3 = 0.f;
        for (int mk = 0; mk < 32; ++mk) {
            int idx = ((mk >> 4) * 4 + vks) * 64 + vq * 16 + (mk & 15);
            uint2 vu = *(const uint2*)(Vfrag + idx * 8 + vj);
            float a = Lg[nl * 33 + mk];
            sa0 = fmaf(a, blo(vu.x), sa0);
            sa1 = fmaf(a, bhi(vu.x), sa1);
            sa2 = fmaf(a, blo(vu.y), sa2);
            sa3 = fmaf(a, bhi(vu.y), sa3);
        }
        uint2 st;
        st.x = pack2(sa0, sa1);
        st.y = pack2(sa2, sa3);
        *(uint2*)(Sfrag + (vks * 64 + vq * 16 + nl) * 8 + vj) = st;
    }
    __syncthreads();

    // ---- P7: Theta MFMA (16 rows; 1 col-tile per wave) -> ThOut (Kfrag region) ----
    {
        f32x4 aT = {0.f, 0.f, 0.f, 0.f};
#pragma unroll
        for (int ks = 0; ks < 4; ++ks) {
            bf16x8 av = *(const bf16x8*)(Sfrag + (ks * 64 + lane) * 8);
            aT = __builtin_amdgcn_mfma_f32_16x16x32_bf16(av, Wf[6144 + (w * 4 + ks) * 64 + lane], aT, 0, 0, 0);
        }
        int colc = w * 16 + col0;
#pragma unroll
        for (int reg = 0; reg < 4; ++reg)
            ThOut[(quad * 4 + reg) * 128 + colc] = aT[reg];
    }
    __syncthreads();

    // ---- P8: y = x + ThOut; LayerNorm; mask; store (1 row x 4 cols per thread) ----
    {
        const int d0 = m3 * 4;
        float4 g4  = *(const float4*)(gma + d0);
        float4 be4 = *(const float4*)(bta + d0);
        float4 th = *(const float4*)(ThOut + nl * 128 + d0);
        float y0 = th.x + xreg.x, y1 = th.y + xreg.y;
        float y2 = th.z + xreg.z, y3 = th.w + xreg.w;
        float s  = (y0 + y1) + (y2 + y3);
        float s2 = (y0*y0 + y1*y1) + (y2*y2 + y3*y3);
#pragma unroll
        for (int off = 1; off < 32; off <<= 1) {
            s  += __shfl_xor(s,  off, 64);
            s2 += __shfl_xor(s2, off, 64);
        }
        float mu   = s * 0.0078125f;
        float var  = s2 * 0.0078125f - mu * mu;
        float rstd = rsqrtf(var + 1e-5f);
        float msk  = (maskrow[ng] != 0.f) ? 0.f : 1.f;
        float4 o;
        o.x = ((y0 - mu) * rstd * g4.x + be4.x) * msk;
        o.y = ((y1 - mu) * rstd * g4.y + be4.y) * msk;
        o.z = ((y2 - mu) * rstd * g4.z + be4.z) * msk;
        o.w = ((y3 - mu) * rstd * g4.w + be4.w) * msk;
        *(float4*)(out + ((size_t)((b_ * 32 + ng) * 64 + t_)) * 128 + d0) = o;
    }
}

extern "C" void kernel_launch(void* const* d_in, const int* in_sizes, int n_in,
                              void* d_out, int out_size, void* d_ws, size_t ws_size,
                              hipStream_t stream) {
    const float* x        = (const float*)d_in[0];
    const float* edge     = (const float*)d_in[1];
    const float* A_prior  = (const float*)d_in[2];
    const unsigned char* pad_mask = (const unsigned char*)d_in[3];
    const float* Wq       = (const float*)d_in[4];
    const float* Wk       = (const float*)d_in[5];
    const float* Wv       = (const float*)d_in[6];
    const float* Theta    = (const float*)d_in[7];
    const float* Wfuse    = (const float*)d_in[8];
    const float* W1       = (const float*)d_in[9];
    const float* b1       = (const float*)d_in[10];
    const float* W2       = (const float*)d_in[11];
    const float* b2       = (const float*)d_in[12];
    const float* gma      = (const float*)d_in[13];
    const float* bta      = (const float*)d_in[14];
    const float* physw    = (const float*)d_in[15];
    const float* priorw   = (const float*)d_in[16];
    float* out = (float*)d_out;

    unsigned short* Wfrag = (unsigned short*)d_ws;   // 73728 shorts = 144 KB

    k0a_pack_w<<<dim3(32), dim3(256), 0, stream>>>(Wq, Wk, Wv, Theta, Wfrag);
    k0b_compose<<<dim3(8), dim3(256), 0, stream>>>(Wq, Wk, W1, Wfrag);
    gnn_fused<<<dim3(1024), dim3(512), 0, stream>>>(
        x, edge, A_prior, pad_mask, Wfrag, Wfuse,
        W1, b1, W2, b2, gma, bta, physw, priorw, out);
}

// Round 12
// 285.513 us; speedup vs baseline: 1.1001x; 1.1001x over previous
//
#include <hip/hip_runtime.h>

// B=8, N=32, T=64, D=128, E=4, H=32, BT=512
// R12 = exact revert to R9 (verified PASS, 190 us dispatch / 285 us total):
// half-block structure (grid 1024, 16 Q-rows/block) at 4 blocks/CU,
// fp32 Q/K in LDS + fp32 VALU QK^T content; MFMA for projections + Theta.
// Rationale: R10/R11 experiments showed <=5% upside beyond this point
// (occupancy-driven BW gain saturates at ~3.1 TB/s) against repeated
// scheduling-sensitive correctness failures in the 512-thread variants.

typedef __bf16 bf16x8 __attribute__((ext_vector_type(8)));
typedef float  f32x4  __attribute__((ext_vector_type(4)));

static __device__ __forceinline__ unsigned short f2bf(float f) {
    unsigned u = __float_as_uint(f);
    u += 0x7fffu + ((u >> 16) & 1u);        // RNE
    return (unsigned short)(u >> 16);
}
static __device__ __forceinline__ float bf2f(unsigned short u) {
    return __uint_as_float(((unsigned)u) << 16);
}
static __device__ __forceinline__ unsigned pack2(float a, float b) {
    return (unsigned)f2bf(a) | ((unsigned)f2bf(b) << 16);
}

// Wfrag (16B chunks): [0,2048) Wq | [2048,4096) Wk | [4096,6144) Wv |
// [6144,8192) Theta | chunk 8192+: Cq=W1q@Wq (512), chunk 8704+: Ck=W1k@Wk (512).
// B-frag chunk (nt*4+ks)*64+lane holds B[k=j][n]: n = nt*16+(lane&15),
// j = ks*32+(lane>>4)*8 + (0..7).
__global__ __launch_bounds__(256) void k0a_pack_w(
    const float* __restrict__ Wq, const float* __restrict__ Wk,
    const float* __restrict__ Wv, const float* __restrict__ Theta,
    unsigned short* __restrict__ Wfrag)
{
    int gid = blockIdx.x * 256 + threadIdx.x;      // 0..8191
    int g = gid >> 11, c = gid & 2047;
    int ntk = c >> 6, lane = c & 63;
    int i = (ntk >> 2) * 16 + (lane & 15);
    int j = (ntk & 3) * 32 + (lane >> 4) * 8;
    const float* src = (g == 0 ? Wq : g == 1 ? Wk : g == 2 ? Wv : Theta) + (size_t)i * 128 + j;
    float4 a = *(const float4*)(src);
    float4 b = *(const float4*)(src + 4);
    uint4 pk;
    pk.x = pack2(a.x, a.y); pk.y = pack2(a.z, a.w);
    pk.z = pack2(b.x, b.y); pk.w = pack2(b.z, b.w);
    *(uint4*)(Wfrag + (size_t)gid * 8) = pk;
}

__global__ __launch_bounds__(256, 1) void k0b_compose(
    const float* __restrict__ Wq, const float* __restrict__ Wk,
    const float* __restrict__ W1, unsigned short* __restrict__ Wfrag)
{
    __shared__ __align__(16) float Ws[128 * 132];
    __shared__ __align__(16) float W1s[8 * 128];
    const int tid = threadIdx.x;
    const int mat   = blockIdx.x & 1;
    const int hbase = (blockIdx.x >> 1) * 8;
    const float* Wsel = mat ? Wk : Wq;
#pragma unroll
    for (int q = 0; q < 16; ++q) {
        int f = tid + 256 * q;
        int i = f >> 5, c4 = (f & 31) * 4;
        *(float4*)(Ws + i * 132 + c4) = *(const float4*)(Wsel + (size_t)i * 128 + c4);
    }
#pragma unroll
    for (int q = 0; q < 4; ++q) {
        int f = tid + 256 * q;
        int hl = f >> 7, i = f & 127;
        W1s[hl * 128 + i] = W1[(size_t)(hbase + hl) * 260 + mat * 128 + i];
    }
    __syncthreads();
    const int hl = tid >> 5;
    const int h  = hbase + hl;
    const int j0 = (tid & 31) * 4;
    float4 acc = {0.f, 0.f, 0.f, 0.f};
    for (int i = 0; i < 128; ++i) {
        float c = W1s[hl * 128 + i];
        float4 w = *(const float4*)(Ws + i * 132 + j0);
        acc.x = fmaf(c, w.x, acc.x); acc.y = fmaf(c, w.y, acc.y);
        acc.z = fmaf(c, w.z, acc.z); acc.w = fmaf(c, w.w, acc.w);
    }
    const int nt = h >> 4;
    const unsigned base = 65536u + (unsigned)mat * 4096u;   // shorts
    float av[4] = {acc.x, acc.y, acc.z, acc.w};
#pragma unroll
    for (int jj = 0; jj < 4; ++jj) {
        int j = j0 + jj;
        int lane = (h & 15) | (((j >> 3) & 3) << 4);
        int ks = j >> 5, vj = j & 7;
        Wfrag[base + (unsigned)((nt * 4 + ks) * 64 + lane) * 8 + vj] = f2bf(av[jj]);
    }
}

__global__ __launch_bounds__(256, 4)
void gnn_fused(const float* __restrict__ x,
               const float* __restrict__ edge,
               const float* __restrict__ A_prior,
               const unsigned char* __restrict__ pad_mask,
               const unsigned short* __restrict__ Wfrag,
               const float* __restrict__ Wfuse,
               const float* __restrict__ W1,
               const float* __restrict__ b1,
               const float* __restrict__ W2,
               const float* __restrict__ b2,
               const float* __restrict__ gma,
               const float* __restrict__ bta,
               const float* __restrict__ physw,
               const float* __restrict__ priorw,
               float* __restrict__ out)
{
    __shared__ __align__(16) unsigned char arena[39648];
    // R_A [0,8192):      Zfrag bf16 A-frags (P0-P1 reads) -> Qs fp32 16x128 (P1w-P3) -> Sfrag bf16 (P6-P7)
    // R_B [8192,25088):  Ks fp32 32x132
    // R_C [25088,33280): Vfrag bf16 (P1w-P6) -> ThOut fp32 16x128 (P7-P8)
    // R_D [33280,38720): Lg fp32 16x33 | hqT bf16 [h][n] stride 18 | hks bf16 [m][h] stride 34
    unsigned short* Zfrag = (unsigned short*)(arena);
    float*          Qs    = (float*)(arena);
    unsigned short* Sfrag = (unsigned short*)(arena);
    float*          Ks    = (float*)(arena + 8192);
    unsigned short* Vfrag = (unsigned short*)(arena + 25088);
    float*          ThOut = (float*)(arena + 25088);
    float*          Lg    = (float*)(arena + 33280);
    unsigned short* hqT   = (unsigned short*)(arena + 35392);
    unsigned short* hks   = (unsigned short*)(arena + 36544);
    float4* W1e_s  = (float4*)(arena + 38720);
    float*  W2_s   = (float*)(arena + 39232);
    float*  b1s    = (float*)(arena + 39360);
    float*  maskrow= (float*)(arena + 39488);
    float*  Wf_s   = (float*)(arena + 39616);

    const int tid  = threadIdx.x;
    const int bt   = blockIdx.x >> 1;
    const int half = blockIdx.x & 1;
    const int b_ = bt >> 6, t_ = bt & 63;
    const float pw  = physw[0];
    const float rw_ = priorw[0];
    const float b2v = b2[0];

    // ---- P0: prefetch edge/prior (2 rows/thread); stage Z A-frags; small weights ----
    const int m3 = tid & 31, n23 = tid >> 5;
    float4 e4[2];
    float pr5[2][5];
#pragma unroll
    for (int r = 0; r < 2; ++r) {
        int ng = half * 16 + n23 * 2 + r;
        e4[r] = *(const float4*)(edge + (((size_t)bt * 32 + ng) * 32 + m3) * 4);
        size_t pb = (((size_t)bt * 32 + ng) * 32 + m3) * 5;
#pragma unroll
        for (int j5 = 0; j5 < 5; ++j5) pr5[r][j5] = A_prior[pb + j5];
    }
#pragma unroll
    for (int it = 0; it < 2; ++it) {
        int f = tid + 256 * it;             // chunk 0..511
        int lane9 = f & 63, ntk = f >> 6;
        int mm = lane9 & 15, qq = lane9 >> 4;
        int n = (ntk >> 2) * 16 + mm;
        int d = (ntk & 3) * 32 + qq * 8;
        const float* xr = x + ((size_t)((b_ * 32 + n) * 64 + t_)) * 128 + d;
        float4 a = *(const float4*)(xr);
        float4 b = *(const float4*)(xr + 4);
        uint4 pk;
        pk.x = pack2(a.x, a.y); pk.y = pack2(a.z, a.w);
        pk.z = pack2(b.x, b.y); pk.w = pack2(b.z, b.w);
        *(uint4*)(Zfrag + f * 8) = pk;
    }
    if (tid < 32) {
        int h = tid;
        W1e_s[h] = *(const float4*)(W1 + (size_t)h * 260 + 256);
        W2_s[h]  = W2[h];
        b1s[h]   = b1[h];
        maskrow[h] = pad_mask[b_ * 32 + h] ? 1.f : 0.f;
        if (h < 5) Wf_s[h] = Wfuse[h];
    }
    __syncthreads();

    const int wv = tid >> 6, lane = tid & 63;
    const int quad = lane >> 4, col0 = lane & 15;
    const bf16x8* Wf = (const bf16x8*)Wfrag;

    // ---- P1: K,V (32 tok), Q (16 rows), hq, hk — MFMA; Q/K stored fp32 ----
    {
        const int Mtk = wv & 1;
        const int ng4 = (wv >> 1) * 4;
        f32x4 zero = {0.f, 0.f, 0.f, 0.f};
        f32x4 aK[4] = {zero, zero, zero, zero};
        f32x4 aV[4] = {zero, zero, zero, zero};
        f32x4 aQ[2] = {zero, zero};
        f32x4 aHq = zero, aHk = zero;
#pragma unroll
        for (int ks = 0; ks < 4; ++ks) {
            bf16x8 avK = *(const bf16x8*)(Zfrag + ((Mtk * 4 + ks) * 64 + lane) * 8);
            bf16x8 avQ = *(const bf16x8*)(Zfrag + ((half * 4 + ks) * 64 + lane) * 8);
#pragma unroll
            for (int nt = 0; nt < 4; ++nt) {
                int bi = ((ng4 + nt) * 4 + ks) * 64 + lane;
                aK[nt] = __builtin_amdgcn_mfma_f32_16x16x32_bf16(avK, Wf[bi + 2048], aK[nt], 0, 0, 0);
                aV[nt] = __builtin_amdgcn_mfma_f32_16x16x32_bf16(avK, Wf[bi + 4096], aV[nt], 0, 0, 0);
            }
#pragma unroll
            for (int nt = 0; nt < 2; ++nt) {
                int bq = ((wv * 2 + nt) * 4 + ks) * 64 + lane;
                aQ[nt] = __builtin_amdgcn_mfma_f32_16x16x32_bf16(avQ, Wf[bq], aQ[nt], 0, 0, 0);
            }
            if (wv < 2)
                aHq = __builtin_amdgcn_mfma_f32_16x16x32_bf16(avQ, Wf[8192 + (wv * 4 + ks) * 64 + lane], aHq, 0, 0, 0);
            aHk = __builtin_amdgcn_mfma_f32_16x16x32_bf16(avK, Wf[8704 + ((wv >> 1) * 4 + ks) * 64 + lane], aHk, 0, 0, 0);
        }
        __syncthreads();   // all Zfrag reads complete; R_A may be overwritten (Qs)
#pragma unroll
        for (int nt = 0; nt < 4; ++nt) {
            int colc = (ng4 + nt) * 16 + col0;
            int vks = colc >> 5, vq = (colc >> 3) & 3, vj = colc & 7;
#pragma unroll
            for (int reg = 0; reg < 4; ++reg) {
                int row = Mtk * 16 + quad * 4 + reg;          // key token 0..31
                Ks[row * 132 + colc] = aK[nt][reg];
                int idx = (Mtk * 4 + vks) * 64 + vq * 16 + (quad * 4 + reg);
                Vfrag[idx * 8 + vj] = f2bf(aV[nt][reg]);
            }
        }
#pragma unroll
        for (int nt = 0; nt < 2; ++nt) {
            int colc = (wv * 2 + nt) * 16 + col0;
#pragma unroll
            for (int reg = 0; reg < 4; ++reg)
                Qs[(quad * 4 + reg) * 128 + colc] = aQ[nt][reg];  // local Q row 0..15
        }
        if (wv < 2) {
            int h = wv * 16 + col0;
#pragma unroll
            for (int reg = 0; reg < 4; ++reg)
                hqT[h * 18 + (quad * 4 + reg)] = f2bf(aHq[reg] + b1s[h]);
        }
        {
            int h = (wv >> 1) * 16 + col0;
#pragma unroll
            for (int reg = 0; reg < 4; ++reg)
                hks[(Mtk * 16 + quad * 4 + reg) * 34 + h] = f2bf(aHk[reg]);
        }
    }
    __syncthreads();

    // ---- P3: logits = QK^T/sqrt(d) (fp32 VALU) + pw*phys + rw*log(prior), masked ----
    {
        const int m = m3, n2 = n23;
        const float* krow = Ks + m * 132;
        const float* q0 = Qs + (n2 * 2) * 128;
        const float* q1 = Qs + (n2 * 2 + 1) * 128;
        float acc0 = 0.f, acc1 = 0.f;
        for (int j = 0; j < 128; j += 4) {
            float4 k4 = *(const float4*)(krow + j);
            float4 qa = *(const float4*)(q0 + j);
            float4 qb = *(const float4*)(q1 + j);
            acc0 = fmaf(qa.x, k4.x, fmaf(qa.y, k4.y, fmaf(qa.z, k4.z, fmaf(qa.w, k4.w, acc0))));
            acc1 = fmaf(qb.x, k4.x, fmaf(qb.y, k4.y, fmaf(qb.z, k4.z, fmaf(qb.w, k4.w, acc1))));
        }
        float pacc[2] = {0.f, 0.f};
        for (int h = 0; h < 32; ++h) {
            float4 we = W1e_s[h];
            float w2v = W2_s[h];
            float hkv = bf2f(hks[m * 34 + h]);
            float hq0 = bf2f(hqT[h * 18 + n2 * 2]);
            float hq1 = bf2f(hqT[h * 18 + n2 * 2 + 1]);
            float he0 = fmaf(e4[0].x, we.x, fmaf(e4[0].y, we.y, fmaf(e4[0].z, we.z, e4[0].w * we.w)));
            float he1 = fmaf(e4[1].x, we.x, fmaf(e4[1].y, we.y, fmaf(e4[1].z, we.z, e4[1].w * we.w)));
            pacc[0] = fmaf(fmaxf(hq0 + hkv + he0, 0.f), w2v, pacc[0]);
            pacc[1] = fmaf(fmaxf(hq1 + hkv + he1, 0.f), w2v, pacc[1]);
        }
        float cont[2] = {acc0, acc1};
#pragma unroll
        for (int r = 0; r < 2; ++r) {
            int nloc = n2 * 2 + r, ng = half * 16 + nloc;
            float pr = pr5[r][0]*Wf_s[0] + pr5[r][1]*Wf_s[1] + pr5[r][2]*Wf_s[2]
                     + pr5[r][3]*Wf_s[3] + pr5[r][4]*Wf_s[4];
            if (!(fabsf(pr) < 1e30f)) pr = 0.f;
            pr = fmaxf(pr, 0.f);
            float lg = cont[r] * 0.08838834764831845f
                     + pw * (pacc[r] + b2v) + rw_ * __logf(pr + 1e-6f);
            if (maskrow[ng] != 0.f || maskrow[m] != 0.f) lg = -1e9f;
            Lg[nloc * 33 + m] = lg;
        }
    }
    __syncthreads();

    // ---- P4: softmax (16 rows) ----
    if (tid < 16) {
        const int n = tid;
        float mx = -3.4e38f;
        for (int m2 = 0; m2 < 32; ++m2) mx = fmaxf(mx, Lg[n * 33 + m2]);
        float s = 0.f;
        for (int m2 = 0; m2 < 32; ++m2) {
            float e = __expf(Lg[n * 33 + m2] - mx);
            Lg[n * 33 + m2] = e; s += e;
        }
        float inv = 1.f / s;
        for (int m2 = 0; m2 < 32; ++m2) Lg[n * 33 + m2] *= inv;
    }
    __syncthreads();

    // ---- P6: spatial = alpha @ V (2 rows/thread) -> bf16 A-frags into Sfrag (R_A; Qs dead) ----
    {
        const int d0 = (tid & 31) * 4, nl0 = (tid >> 5) * 2;
        const int vks = d0 >> 5, vq = (d0 >> 3) & 3, vj = d0 & 7;
        float sa[2][4] = {{0,0,0,0},{0,0,0,0}};
        for (int m = 0; m < 32; ++m) {
            int idx = ((m >> 4) * 4 + vks) * 64 + vq * 16 + (m & 15);
            const unsigned short* vp = Vfrag + idx * 8 + vj;
            float v0 = bf2f(vp[0]), v1 = bf2f(vp[1]), v2 = bf2f(vp[2]), v3 = bf2f(vp[3]);
            float a0 = Lg[nl0 * 33 + m], a1 = Lg[(nl0 + 1) * 33 + m];
            sa[0][0]=fmaf(a0,v0,sa[0][0]); sa[0][1]=fmaf(a0,v1,sa[0][1]);
            sa[0][2]=fmaf(a0,v2,sa[0][2]); sa[0][3]=fmaf(a0,v3,sa[0][3]);
            sa[1][0]=fmaf(a1,v0,sa[1][0]); sa[1][1]=fmaf(a1,v1,sa[1][1]);
            sa[1][2]=fmaf(a1,v2,sa[1][2]); sa[1][3]=fmaf(a1,v3,sa[1][3]);
        }
#pragma unroll
        for (int r = 0; r < 2; ++r) {
            int nloc = nl0 + r;
            unsigned short* sp = Sfrag + (vks * 64 + vq * 16 + nloc) * 8 + vj;
            sp[0] = f2bf(sa[r][0]); sp[1] = f2bf(sa[r][1]);
            sp[2] = f2bf(sa[r][2]); sp[3] = f2bf(sa[r][3]);
        }
    }
    __syncthreads();

    // ---- P7: Theta MFMA (16 rows) -> ThOut fp32 (R_C; Vfrag dead) ----
    {
        f32x4 aT[2] = {{0.f,0.f,0.f,0.f},{0.f,0.f,0.f,0.f}};
#pragma unroll
        for (int ks = 0; ks < 4; ++ks) {
            bf16x8 av = *(const bf16x8*)(Sfrag + (ks * 64 + lane) * 8);
#pragma unroll
            for (int nt = 0; nt < 2; ++nt)
                aT[nt] = __builtin_amdgcn_mfma_f32_16x16x32_bf16(
                    av, Wf[6144 + ((wv * 2 + nt) * 4 + ks) * 64 + lane], aT[nt], 0, 0, 0);
        }
#pragma unroll
        for (int nt = 0; nt < 2; ++nt) {
            int colc = (wv * 2 + nt) * 16 + col0;
#pragma unroll
            for (int reg = 0; reg < 4; ++reg)
                ThOut[(quad * 4 + reg) * 128 + colc] = aT[nt][reg];
        }
    }
    __syncthreads();

    // ---- P8: y = x + ThOut; LayerNorm; mask; store (2 rows/thread) ----
    {
        const int d0 = (tid & 31) * 4, n2 = tid >> 5;
        float4 g4  = *(const float4*)(gma + d0);
        float4 be4 = *(const float4*)(bta + d0);
#pragma unroll
        for (int r = 0; r < 2; ++r) {
            int nloc = n2 * 2 + r, ng = half * 16 + nloc;
            const float* xr = x + ((size_t)((b_ * 32 + ng) * 64 + t_)) * 128 + d0;
            float4 z  = *(const float4*)(xr);
            float4 th = *(const float4*)(ThOut + nloc * 128 + d0);
            float y0 = th.x + z.x, y1 = th.y + z.y, y2 = th.z + z.z, y3 = th.w + z.w;
            float s  = (y0 + y1) + (y2 + y3);
            float s2 = (y0*y0 + y1*y1) + (y2*y2 + y3*y3);
#pragma unroll
            for (int off = 1; off < 32; off <<= 1) {
                s  += __shfl_xor(s,  off, 64);
                s2 += __shfl_xor(s2, off, 64);
            }
            float mu   = s * 0.0078125f;
            float var  = s2 * 0.0078125f - mu * mu;
            float rstd = rsqrtf(var + 1e-5f);
            float msk  = (maskrow[ng] != 0.f) ? 0.f : 1.f;
            float4 o;
            o.x = ((y0 - mu) * rstd * g4.x + be4.x) * msk;
            o.y = ((y1 - mu) * rstd * g4.y + be4.y) * msk;
            o.z = ((y2 - mu) * rstd * g4.z + be4.z) * msk;
            o.w = ((y3 - mu) * rstd * g4.w + be4.w) * msk;
            *(float4*)(out + ((size_t)((b_ * 32 + ng) * 64 + t_)) * 128 + d0) = o;
        }
    }
}

extern "C" void kernel_launch(void* const* d_in, const int* in_sizes, int n_in,
                              void* d_out, int out_size, void* d_ws, size_t ws_size,
                              hipStream_t stream) {
    const float* x        = (const float*)d_in[0];
    const float* edge     = (const float*)d_in[1];
    const float* A_prior  = (const float*)d_in[2];
    const unsigned char* pad_mask = (const unsigned char*)d_in[3];
    const float* Wq       = (const float*)d_in[4];
    const float* Wk       = (const float*)d_in[5];
    const float* Wv       = (const float*)d_in[6];
    const float* Theta    = (const float*)d_in[7];
    const float* Wfuse    = (const float*)d_in[8];
    const float* W1       = (const float*)d_in[9];
    const float* b1       = (const float*)d_in[10];
    const float* W2       = (const float*)d_in[11];
    const float* b2       = (const float*)d_in[12];
    const float* gma      = (const float*)d_in[13];
    const float* bta      = (const float*)d_in[14];
    const float* physw    = (const float*)d_in[15];
    const float* priorw   = (const float*)d_in[16];
    float* out = (float*)d_out;

    unsigned short* Wfrag = (unsigned short*)d_ws;   // 73728 shorts = 144 KB

    k0a_pack_w<<<dim3(32), dim3(256), 0, stream>>>(Wq, Wk, Wv, Theta, Wfrag);
    k0b_compose<<<dim3(8), dim3(256), 0, stream>>>(Wq, Wk, W1, Wfrag);
    gnn_fused<<<dim3(1024), dim3(256), 0, stream>>>(
        x, edge, A_prior, pad_mask, Wfrag, Wfuse,
        W1, b1, W2, b2, gma, bta, physw, priorw, out);
}